// Round 9
// baseline (446.401 us; speedup 1.0000x reference)
//
#include <hip/hip_runtime.h>

// GCN: z1 = relu(Agg(x@W1)+b1); out = ((P·Â·z1)@W2 + b2)@Wfc + bfc
//   (pooling commuted before W2).  psum[g] = sum_s c_s[g]·z1[s].
// Layer 1: gather via CSR-by-dst (bf16 H, MFMA GEMM), 16-edge software-
//   pipelined gather (latency-bound => MLP).
// Layer 2: per-block coefficient rows in LDS from CSC slice (u32-packed
//   {g,bf16 nrm}), contracted against streamed z1.
// Build: counting-sort via atomic return values; 2 atomics/edge is the floor
// (~67us per atomic-per-edge pass, memory-side RMW constant — rounds 3/7/8).

constexpr int FDIM = 128;
constexpr int SC   = 128;    // k_cgemm nodes per block

typedef __attribute__((ext_vector_type(8))) short short8v;
typedef __attribute__((ext_vector_type(4))) float f32x4;

__device__ __forceinline__ ushort f2bf(float f) {
    uint u = __float_as_uint(f);
    return (ushort)((u + 0x7fffu + ((u >> 16) & 1u)) >> 16);
}
__device__ __forceinline__ float bf2f_lo(uint d) { return __uint_as_float(d << 16); }
__device__ __forceinline__ float bf2f_hi(uint d) { return __uint_as_float(d & 0xffff0000u); }

// ---------------- init: zero histograms ----------------
__global__ __launch_bounds__(256) void k_init(unsigned long long* packed,
                                              uint* ocnt, int NN) {
    int i = blockIdx.x * 256 + threadIdx.x;
    if (i < NN) { packed[i] = 0ULL; ocnt[i] = 0u; }
}

// ---------------- fused histogram + position assignment ----------------
__global__ __launch_bounds__(256) void k_hist2(const int* __restrict__ src,
                                               const int* __restrict__ dst,
                                               const float* __restrict__ ew,
                                               unsigned long long* __restrict__ packed,
                                               uint* __restrict__ ocnt,
                                               uint* __restrict__ aux, int E) {
    int e = blockIdx.x * 256 + threadIdx.x;
    if (e < E) {
        int d = dst[e], s = src[e];
        uint fix = __float2uint_rn(ew[e] * 16777216.0f);   // 2^24 fixed point
        unsigned long long old =
            atomicAdd(&packed[d], (1ULL << 32) | (unsigned long long)fix);
        uint pos = (uint)(old >> 32);
        uint opos = atomicAdd(&ocnt[s], 1u);
        aux[e] = (pos << 16) | (opos & 0xffffu);
    }
}

// ---------------- merge: packed -> cnt, dinv ----------------
__global__ __launch_bounds__(256) void k_merge(const unsigned long long* __restrict__ packed,
                                               int* __restrict__ cnt,
                                               float* __restrict__ dinv, int NN) {
    int n = blockIdx.x * 256 + threadIdx.x;
    if (n >= NN) return;
    unsigned long long v = packed[n];
    cnt[n] = (int)(v >> 32);
    float deg = 1.0f + (float)(v & 0xffffffffULL) * 5.9604644775390625e-8f;  // 2^-24
    dinv[n] = rsqrtf(deg);
}

// ---------------- exclusive scan (3-kernel, chunk=1024) ----------------
__global__ __launch_bounds__(256) void k_bsum(const int* __restrict__ cnt, int* bsum, int NN) {
    __shared__ int lds[256];
    int b = blockIdx.x, t = threadIdx.x;
    int base = b * 1024;
    int s = 0;
#pragma unroll
    for (int j = 0; j < 4; j++) {
        int i = base + j * 256 + t;
        if (i < NN) s += cnt[i];
    }
    lds[t] = s;
    __syncthreads();
    for (int off = 128; off > 0; off >>= 1) {
        if (t < off) lds[t] += lds[t + off];
        __syncthreads();
    }
    if (t == 0) bsum[b] = lds[0];
}

__global__ __launch_bounds__(256) void k_btops(const int* bsum, int* boff, int* rowptr,
                                               int NB, int NN) {
    __shared__ int lds[256];
    int t = threadIdx.x;
    if (t < NB) lds[t] = bsum[t];
    __syncthreads();
    if (t == 0) {
        int run = 0;
        for (int i = 0; i < NB; i++) { int v = lds[i]; boff[i] = run; run += v; }
        rowptr[NN] = run;   // == E
    }
}

__global__ __launch_bounds__(256) void k_scan(const int* __restrict__ cnt,
                                              const int* __restrict__ boff,
                                              int* rowptr, int NN) {
    __shared__ int lds[2][256];
    int b = blockIdx.x, t = threadIdx.x;
    int base = b * 1024 + t * 4;
    int v[4]; int s = 0;
#pragma unroll
    for (int j = 0; j < 4; j++) { v[j] = (base + j < NN) ? cnt[base + j] : 0; s += v[j]; }
    lds[0][t] = s;
    __syncthreads();
    int cur = 0;
    for (int off = 1; off < 256; off <<= 1) {
        int val = lds[cur][t];
        if (t >= off) val += lds[cur][t - off];
        lds[cur ^ 1][t] = val;
        __syncthreads();
        cur ^= 1;
    }
    int excl = lds[cur][t] - s + boff[b];
#pragma unroll
    for (int j = 0; j < 4; j++) {
        if (base + j < NN) rowptr[base + j] = excl;
        excl += v[j];
    }
}

// ---------------- CSR(dst) + CSC(src) fill — store-only, no atomics ----------
// csc packed u32: {batch[dst] << 16 | bf16(nrm)}
__global__ __launch_bounds__(256) void k_fill2(const int* __restrict__ src,
                                               const int* __restrict__ dst,
                                               const float* __restrict__ ew,
                                               const uint* __restrict__ aux,
                                               const float* __restrict__ dinv,
                                               const int* __restrict__ batch,
                                               const int* __restrict__ rowptr,
                                               const int* __restrict__ cscptr,
                                               uint2* __restrict__ csr,
                                               uint* __restrict__ csc, int E) {
    int e = blockIdx.x * 256 + threadIdx.x;
    if (e < E) {
        int d = dst[e], s = src[e];
        uint a = aux[e];
        int pos = (int)(a >> 16), opos = (int)(a & 0xffffu);
        float nrm = dinv[s] * ew[e] * dinv[d];
        csr[rowptr[d] + pos]  = make_uint2((uint)s, __float_as_uint(nrm));
        csc[cscptr[s] + opos] = ((uint)batch[d] << 16) | (uint)f2bf(nrm);
    }
}

// ---------------- graph node counts from sorted batch (binary search) --------
__global__ __launch_bounds__(64) void k_gcnt(const int* __restrict__ batch,
                                             int* __restrict__ gcnt, int NN, int G) {
    int g = threadIdx.x;
    if (g >= G) return;
    auto lb = [&](int v) {
        int lo = 0, hi = NN;
        while (lo < hi) { int mid = (lo + hi) >> 1; if (batch[mid] < v) lo = mid + 1; else hi = mid; }
        return lo;
    };
    gcnt[g] = lb(g + 1) - lb(g);
}

// ---------------- W[128][128] fp32 -> Wt[n][k] bf16 (transpose+cast) ---------
__global__ __launch_bounds__(256) void k_wt(const float* __restrict__ W,
                                            ushort* __restrict__ Wt) {
    int t = threadIdx.x;
    for (int i = t; i < FDIM * FDIM; i += 256) {
        int k = i >> 7, n = i & 127;
        Wt[n * FDIM + k] = f2bf(W[i]);
    }
}

// ---------------- bf16 MFMA GEMM: H[N,128] = X[N,128] @ Wt^T -----------------
__global__ __launch_bounds__(256) void k_gemm(const float* __restrict__ X,
                                              const ushort* __restrict__ Wt,
                                              ushort* __restrict__ H, int N) {
    int t = threadIdx.x;
    int wave = t >> 6, l = t & 63;
    int m = l & 15, kg = (l >> 4) * 8;
    int r0 = blockIdx.x * 64 + wave * 16;
    int row = r0 + m;
    short8v a[4];
    if (row < N) {
#pragma unroll
        for (int ks = 0; ks < 4; ks++) {
            const float* xp = X + (size_t)row * FDIM + ks * 32 + kg;
            float4 f0 = *(const float4*)xp;
            float4 f1 = *(const float4*)(xp + 4);
            short8v av;
            av[0] = (short)f2bf(f0.x); av[1] = (short)f2bf(f0.y);
            av[2] = (short)f2bf(f0.z); av[3] = (short)f2bf(f0.w);
            av[4] = (short)f2bf(f1.x); av[5] = (short)f2bf(f1.y);
            av[6] = (short)f2bf(f1.z); av[7] = (short)f2bf(f1.w);
            a[ks] = av;
        }
    } else {
#pragma unroll
        for (int ks = 0; ks < 4; ks++) a[ks] = (short8v)0;
    }
    int orow = r0 + (l >> 4) * 4;
#pragma unroll
    for (int c = 0; c < 8; c++) {
        f32x4 acc = {0.f, 0.f, 0.f, 0.f};
#pragma unroll
        for (int ks = 0; ks < 4; ks++) {
            short8v b = *(const short8v*)(Wt + (size_t)(c * 16 + m) * FDIM + ks * 32 + kg);
            acc = __builtin_amdgcn_mfma_f32_16x16x32_bf16(a[ks], b, acc, 0, 0, 0);
        }
#pragma unroll
        for (int j = 0; j < 4; j++)
            if (orow + j < N) H[(size_t)(orow + j) * FDIM + c * 16 + m] = f2bf(acc[j]);
    }
}

// ---------------- layer-1 gather aggregation v4 (16-edge pipeline) -----------
// 1 node per wave-iter; 4 edge-slots per lane-group (eg=l>>4), 16 lanes x
// 8 bf16 feats. Next batch's csr descriptors prefetched while current H-row
// loads + FMAs are in flight (breaks the csr->H dependent chain).
__global__ __launch_bounds__(256) void k_agg(const ushort* __restrict__ H,
                                             const int* __restrict__ rowptr,
                                             const uint2* __restrict__ csr,
                                             const float* __restrict__ dinv,
                                             const float* __restrict__ bias,
                                             ushort* __restrict__ Z, int NN) {
    int t = threadIdx.x;
    int wave = t >> 6, l = t & 63;
    int eg = l >> 4, li = l & 15;
    int f0 = li * 8;

    for (int it = 0; it < 4; ++it) {
        int n = blockIdx.x * 16 + wave * 4 + it;
        if (n >= NN) continue;
        float acc[8];
        if (eg == 0) {
            float di = dinv[n];
            float sw = di * di;
            uint4 hv = *(const uint4*)(H + (size_t)n * FDIM + f0);
            acc[0] = sw * bf2f_lo(hv.x); acc[1] = sw * bf2f_hi(hv.x);
            acc[2] = sw * bf2f_lo(hv.y); acc[3] = sw * bf2f_hi(hv.y);
            acc[4] = sw * bf2f_lo(hv.z); acc[5] = sw * bf2f_hi(hv.z);
            acc[6] = sw * bf2f_lo(hv.w); acc[7] = sw * bf2f_hi(hv.w);
        } else {
#pragma unroll
            for (int j = 0; j < 8; j++) acc[j] = 0.0f;
        }
        int rs = rowptr[n], re = rowptr[n + 1];
        if (rs < re) {
            uint2 p[4];
#pragma unroll
            for (int j = 0; j < 4; j++)
                p[j] = csr[min(rs + j * 4 + eg, re - 1)];
#pragma unroll 1
            for (int e = rs; e < re; e += 16) {
                uint4 v[4];
#pragma unroll
                for (int j = 0; j < 4; j++)
                    v[j] = *(const uint4*)(H + (size_t)p[j].x * FDIM + f0);
                uint2 pn[4];
                int en = e + 16;
#pragma unroll
                for (int j = 0; j < 4; j++)
                    pn[j] = csr[min(en + j * 4 + eg, re - 1)];
#pragma unroll
                for (int j = 0; j < 4; j++) {
                    float w = (e + j * 4 + eg < re) ? __uint_as_float(p[j].y) : 0.0f;
                    acc[0] = fmaf(w, bf2f_lo(v[j].x), acc[0]);
                    acc[1] = fmaf(w, bf2f_hi(v[j].x), acc[1]);
                    acc[2] = fmaf(w, bf2f_lo(v[j].y), acc[2]);
                    acc[3] = fmaf(w, bf2f_hi(v[j].y), acc[3]);
                    acc[4] = fmaf(w, bf2f_lo(v[j].z), acc[4]);
                    acc[5] = fmaf(w, bf2f_hi(v[j].z), acc[5]);
                    acc[6] = fmaf(w, bf2f_lo(v[j].w), acc[6]);
                    acc[7] = fmaf(w, bf2f_hi(v[j].w), acc[7]);
                }
#pragma unroll
                for (int j = 0; j < 4; j++) p[j] = pn[j];
            }
        }
#pragma unroll
        for (int j = 0; j < 8; j++) {
            acc[j] += __shfl_xor(acc[j], 16);
            acc[j] += __shfl_xor(acc[j], 32);
        }
        if (eg == 0) {
#pragma unroll
            for (int j = 0; j < 8; j++) acc[j] = fmaxf(acc[j] + bias[f0 + j], 0.0f);
            uint4 o;
            o.x = (uint)f2bf(acc[0]) | ((uint)f2bf(acc[1]) << 16);
            o.y = (uint)f2bf(acc[2]) | ((uint)f2bf(acc[3]) << 16);
            o.z = (uint)f2bf(acc[4]) | ((uint)f2bf(acc[5]) << 16);
            o.w = (uint)f2bf(acc[6]) | ((uint)f2bf(acc[7]) << 16);
            *(uint4*)(Z + (size_t)n * FDIM + f0) = o;
        }
    }
}

// ---------------- layer-2 fused: coefficient rows in LDS + contraction -------
__global__ __launch_bounds__(256) void k_cgemm(const ushort* __restrict__ Z,
                                               const int* __restrict__ cscptr,
                                               const uint* __restrict__ csc,
                                               const float* __restrict__ dinv,
                                               const int* __restrict__ batch,
                                               float* __restrict__ partial, int NN) {
    __shared__ float crow[SC][65];
    int t = threadIdx.x;
    for (int i = t; i < SC * 65; i += 256) ((float*)crow)[i] = 0.0f;
    __syncthreads();
    int s0 = blockIdx.x * SC;
    if (t < SC) {
        int s = s0 + t;
        if (s < NN) {
            float di = dinv[s];
            crow[t][batch[s]] += di * di;          // self-loop coefficient
            int rs = cscptr[s], re = cscptr[s + 1];
            for (int e = rs; e < re; ++e) {
                uint p = csc[e];
                crow[t][p >> 16] += __uint_as_float((p & 0xffffu) << 16);
            }
        }
    }
    __syncthreads();

    int fq = t & 15, gh = t >> 4;
    int f0 = fq * 8, g0 = gh * 4;
    float acc[4][8];
#pragma unroll
    for (int gi = 0; gi < 4; gi++)
#pragma unroll
        for (int j = 0; j < 8; j++) acc[gi][j] = 0.0f;

    for (int sl = 0; sl < SC; ++sl) {
        int s = s0 + sl;
        if (s >= NN) break;
        short8v zq = *(const short8v*)(Z + (size_t)s * FDIM + f0);
        float zf[8];
#pragma unroll
        for (int j = 0; j < 8; j++)
            zf[j] = __uint_as_float(((uint)(ushort)zq[j]) << 16);
        float c0 = crow[sl][g0 + 0], c1 = crow[sl][g0 + 1];
        float c2 = crow[sl][g0 + 2], c3 = crow[sl][g0 + 3];
#pragma unroll
        for (int j = 0; j < 8; j++) {
            acc[0][j] = fmaf(c0, zf[j], acc[0][j]);
            acc[1][j] = fmaf(c1, zf[j], acc[1][j]);
            acc[2][j] = fmaf(c2, zf[j], acc[2][j]);
            acc[3][j] = fmaf(c3, zf[j], acc[3][j]);
        }
    }
    float* dstp = partial + (size_t)blockIdx.x * 64 * FDIM;
#pragma unroll
    for (int gi = 0; gi < 4; gi++) {
#pragma unroll
        for (int j = 0; j < 8; j += 4)
            *(float4*)&dstp[(g0 + gi) * FDIM + f0 + j] =
                make_float4(acc[gi][j], acc[gi][j + 1], acc[gi][j + 2], acc[gi][j + 3]);
    }
}

// ---------------- two-stage partial reduction ----------------
__global__ __launch_bounds__(256) void k_predA(const float* __restrict__ partial,
                                               float* __restrict__ partial2,
                                               int NBLK, int RED) {
    int r = blockIdx.x >> 5, c = blockIdx.x & 31;
    int cell = c * 256 + threadIdx.x;
    int b0 = r * RED, b1 = min(b0 + RED, NBLK);
    float acc = 0.0f;
    for (int b = b0; b < b1; ++b)
        acc += partial[(size_t)b * 64 * FDIM + cell];
    partial2[(size_t)r * 64 * FDIM + cell] = acc;
}

__global__ __launch_bounds__(128) void k_predB(const float* __restrict__ partial2,
                                               float* __restrict__ psum) {
    int g = blockIdx.x, f = threadIdx.x;
    float acc = 0.0f;
#pragma unroll
    for (int r = 0; r < 8; ++r)
        acc += partial2[(size_t)r * 64 * FDIM + g * FDIM + f];
    psum[g * FDIM + f] = acc;
}

// ---------------- mean + W2 + b2 + Wfc + bfc (two tiny GEMMs fused) ----------
__global__ __launch_bounds__(128) void k_fc2(const float* __restrict__ psum,
                                             const int* __restrict__ gcnt,
                                             const float* __restrict__ W2,
                                             const float* __restrict__ b2,
                                             const float* __restrict__ Wfc,
                                             const float* __restrict__ bfc,
                                             float* __restrict__ out) {
    __shared__ float p[FDIM], t1[FDIM];
    int g = blockIdx.x, f = threadIdx.x;
    float c = (float)max(gcnt[g], 1);
    p[f] = psum[g * FDIM + f] / c;
    __syncthreads();
    float acc = b2[f];
#pragma unroll 8
    for (int k = 0; k < FDIM; k++) acc = fmaf(p[k], W2[k * FDIM + f], acc);
    t1[f] = acc;
    __syncthreads();
    float acc2 = bfc[f];
#pragma unroll 8
    for (int k = 0; k < FDIM; k++) acc2 = fmaf(t1[k], Wfc[k * FDIM + f], acc2);
    out[g * FDIM + f] = acc2;
}

extern "C" void kernel_launch(void* const* d_in, const int* in_sizes, int n_in,
                              void* d_out, int out_size, void* d_ws, size_t ws_size,
                              hipStream_t stream) {
    const float* x    = (const float*)d_in[0];
    const int*   ei   = (const int*)d_in[1];
    const float* ew   = (const float*)d_in[2];
    const int*   batch= (const int*)d_in[3];
    const float* W1   = (const float*)d_in[4];
    const float* b1   = (const float*)d_in[5];
    const float* W2   = (const float*)d_in[6];
    const float* b2   = (const float*)d_in[7];
    const float* Wfc  = (const float*)d_in[8];
    const float* bfc  = (const float*)d_in[9];
    float* out = (float*)d_out;

    int E  = in_sizes[2];       // 1,600,000
    int NN = in_sizes[3];       // 100,000
    int G  = out_size / FDIM;   // 64

    const int* src = ei;
    const int* dst = ei + E;

    char* ws = (char*)d_ws;
    size_t off = 0;
    auto alloc = [&](size_t bytes) -> void* {
        void* p = ws + off;
        off = (off + bytes + 255) & ~(size_t)255;
        return p;
    };
    unsigned long long* packed = (unsigned long long*)alloc((size_t)NN * 8);
    uint*  ocnt    = (uint*)alloc((size_t)NN * 4);
    uint*  aux     = (uint*)alloc((size_t)E * 4);
    int*   cnt     = (int*)alloc((size_t)NN * 4);
    float* dinv    = (float*)alloc((size_t)NN * 4);
    int*   rowptr  = (int*)alloc((size_t)(NN + 1) * 4);
    int*   cscptr  = (int*)alloc((size_t)(NN + 1) * 4);
    int*   bsumA   = (int*)alloc(256 * 4);
    int*   boffA   = (int*)alloc(256 * 4);
    int*   bsumB   = (int*)alloc(256 * 4);
    int*   boffB   = (int*)alloc(256 * 4);
    uint2* csr     = (uint2*)alloc((size_t)E * 8);
    uint*  csc     = (uint*)alloc((size_t)E * 4);
    float* psum    = (float*)alloc((size_t)G * FDIM * 4);
    float* partial2= (float*)alloc((size_t)8 * 64 * FDIM * 4);
    int*   gcnt    = (int*)alloc((size_t)G * 4);
    ushort* Bh     = (ushort*)alloc((size_t)NN * FDIM * 2);   // h1; later partial
    ushort* Bz     = (ushort*)alloc((size_t)NN * FDIM * 2);   // z1
    ushort* Wt1    = (ushort*)alloc((size_t)FDIM * FDIM * 2);
    float* partial = (float*)Bh;   // NBLK*32KB = 25.03MB <= |Bh| = 25.6MB
    (void)ws_size; (void)n_in;

    int nbN = (NN + 255) / 256;
    int nbE = (E + 255) / 256;
    int NB  = (NN + 1023) / 1024;   // 98
    int NBLK = (NN + SC - 1) / SC;  // 782
    int RED  = (NBLK + 7) / 8;      // 98

    k_init<<<nbN, 256, 0, stream>>>(packed, ocnt, NN);
    k_hist2<<<nbE, 256, 0, stream>>>(src, dst, ew, packed, ocnt, aux, E);
    k_merge<<<nbN, 256, 0, stream>>>(packed, cnt, dinv, NN);
    // scan cnt -> rowptr ; ocnt -> cscptr
    k_bsum<<<NB, 256, 0, stream>>>(cnt, bsumA, NN);
    k_btops<<<1, 256, 0, stream>>>(bsumA, boffA, rowptr, NB, NN);
    k_scan<<<NB, 256, 0, stream>>>(cnt, boffA, rowptr, NN);
    k_bsum<<<NB, 256, 0, stream>>>((const int*)ocnt, bsumB, NN);
    k_btops<<<1, 256, 0, stream>>>(bsumB, boffB, cscptr, NB, NN);
    k_scan<<<NB, 256, 0, stream>>>((const int*)ocnt, boffB, cscptr, NN);
    k_fill2<<<nbE, 256, 0, stream>>>(src, dst, ew, aux, dinv, batch,
                                     rowptr, cscptr, csr, csc, E);
    k_gcnt<<<1, 64, 0, stream>>>(batch, gcnt, NN, G);
    k_wt<<<1, 256, 0, stream>>>(W1, Wt1);

    int nbG = (NN + 63) / 64;
    int nbA = (NN + 15) / 16;
    // layer 1: h1 = x@W1 ; z1 = relu(Agg(h1)+b1)
    k_gemm<<<nbG, 256, 0, stream>>>(x, Wt1, Bh, NN);
    k_agg<<<nbA, 256, 0, stream>>>(Bh, rowptr, csr, dinv, b1, Bz, NN);
    // layer 2: per-block LDS coefficient rows, contract against streamed z1
    k_cgemm<<<NBLK, 256, 0, stream>>>(Bz, cscptr, csc, dinv, batch, partial, NN);
    k_predA<<<256, 256, 0, stream>>>(partial, partial2, NBLK, RED);
    k_predB<<<G, 128, 0, stream>>>(partial2, psum);
    // out = ((psum/cnt)@W2 + b2)@Wfc + bfc
    k_fc2<<<G, 128, 0, stream>>>(psum, gcnt, W2, b2, Wfc, bfc, out);
}

// Round 10
// 352.057 us; speedup vs baseline: 1.2680x; 1.2680x over previous
//
#include <hip/hip_runtime.h>

// GCN: z1 = relu(Agg(x@W1)+b1); out = ((P·Â·z1)@W2 + b2)@Wfc + bfc
//   (pooling commuted before W2; P·Â·z1 pooled row-wise over dst).
// ONE CSR (by dst) serves both layers: layer 1 gathers h1 rows; layer 2
// gathers z1 rows with the same structure and pools by batch[dst] (LDS pool,
// batch sorted). CSC path deleted (round-9 lesson: its build cost ~94us >
// the 33us gather it saved).
// Build: 1 atomic/edge (packed u64 count|fix24; return value = CSR slot).
// ~67us per atomic-per-edge pass is the memory-side RMW constant (r3/7/8/9).

constexpr int FDIM = 128;

typedef __attribute__((ext_vector_type(8))) short short8v;
typedef __attribute__((ext_vector_type(4))) float f32x4;

__device__ __forceinline__ ushort f2bf(float f) {
    uint u = __float_as_uint(f);
    return (ushort)((u + 0x7fffu + ((u >> 16) & 1u)) >> 16);
}
__device__ __forceinline__ float bf2f_lo(uint d) { return __uint_as_float(d << 16); }
__device__ __forceinline__ float bf2f_hi(uint d) { return __uint_as_float(d & 0xffff0000u); }

// ---------------- init: zero histogram + psum ----------------
__global__ __launch_bounds__(256) void k_init(unsigned long long* packed,
                                              float* psum, int NN, int PS) {
    int i = blockIdx.x * 256 + threadIdx.x;
    if (i < NN) packed[i] = 0ULL;
    if (i < PS) psum[i] = 0.0f;
}

// ---------------- histogram + CSR position (single atomic/edge) ----------------
__global__ __launch_bounds__(256) void k_hist(const int* __restrict__ dst,
                                              const float* __restrict__ ew,
                                              unsigned long long* __restrict__ packed,
                                              ushort* __restrict__ aux, int E) {
    int e = blockIdx.x * 256 + threadIdx.x;
    if (e < E) {
        int d = dst[e];
        uint fix = __float2uint_rn(ew[e] * 16777216.0f);   // 2^24 fixed point
        unsigned long long old =
            atomicAdd(&packed[d], (1ULL << 32) | (unsigned long long)fix);
        aux[e] = (ushort)(old >> 32);                      // slot in dst bucket
    }
}

// ---------------- merge: packed -> cnt, dinv ----------------
__global__ __launch_bounds__(256) void k_merge(const unsigned long long* __restrict__ packed,
                                               int* __restrict__ cnt,
                                               float* __restrict__ dinv, int NN) {
    int n = blockIdx.x * 256 + threadIdx.x;
    if (n >= NN) return;
    unsigned long long v = packed[n];
    cnt[n] = (int)(v >> 32);
    float deg = 1.0f + (float)(v & 0xffffffffULL) * 5.9604644775390625e-8f;  // 2^-24
    dinv[n] = rsqrtf(deg);
}

// ---------------- exclusive scan (3-kernel, chunk=1024) ----------------
__global__ __launch_bounds__(256) void k_bsum(const int* __restrict__ cnt, int* bsum, int NN) {
    __shared__ int lds[256];
    int b = blockIdx.x, t = threadIdx.x;
    int base = b * 1024;
    int s = 0;
#pragma unroll
    for (int j = 0; j < 4; j++) {
        int i = base + j * 256 + t;
        if (i < NN) s += cnt[i];
    }
    lds[t] = s;
    __syncthreads();
    for (int off = 128; off > 0; off >>= 1) {
        if (t < off) lds[t] += lds[t + off];
        __syncthreads();
    }
    if (t == 0) bsum[b] = lds[0];
}

__global__ __launch_bounds__(256) void k_btops(const int* bsum, int* boff, int* rowptr,
                                               int NB, int NN) {
    __shared__ int lds[256];
    int t = threadIdx.x;
    if (t < NB) lds[t] = bsum[t];
    __syncthreads();
    if (t == 0) {
        int run = 0;
        for (int i = 0; i < NB; i++) { int v = lds[i]; boff[i] = run; run += v; }
        rowptr[NN] = run;   // == E
    }
}

__global__ __launch_bounds__(256) void k_scan(const int* __restrict__ cnt,
                                              const int* __restrict__ boff,
                                              int* rowptr, int NN) {
    __shared__ int lds[2][256];
    int b = blockIdx.x, t = threadIdx.x;
    int base = b * 1024 + t * 4;
    int v[4]; int s = 0;
#pragma unroll
    for (int j = 0; j < 4; j++) { v[j] = (base + j < NN) ? cnt[base + j] : 0; s += v[j]; }
    lds[0][t] = s;
    __syncthreads();
    int cur = 0;
    for (int off = 1; off < 256; off <<= 1) {
        int val = lds[cur][t];
        if (t >= off) val += lds[cur][t - off];
        lds[cur ^ 1][t] = val;
        __syncthreads();
        cur ^= 1;
    }
    int excl = lds[cur][t] - s + boff[b];
#pragma unroll
    for (int j = 0; j < 4; j++) {
        if (base + j < NN) rowptr[base + j] = excl;
        excl += v[j];
    }
}

// ---------------- CSR fill — store-only, no atomics ----------------
__global__ __launch_bounds__(256) void k_fill(const int* __restrict__ src,
                                              const int* __restrict__ dst,
                                              const float* __restrict__ ew,
                                              const ushort* __restrict__ aux,
                                              const float* __restrict__ dinv,
                                              const int* __restrict__ rowptr,
                                              uint2* __restrict__ csr, int E) {
    int e = blockIdx.x * 256 + threadIdx.x;
    if (e < E) {
        int d = dst[e], s = src[e];
        float nrm = dinv[s] * ew[e] * dinv[d];
        csr[rowptr[d] + (int)aux[e]] = make_uint2((uint)s, __float_as_uint(nrm));
    }
}

// ---------------- graph node counts from sorted batch (binary search) --------
__global__ __launch_bounds__(64) void k_gcnt(const int* __restrict__ batch,
                                             int* __restrict__ gcnt, int NN, int G) {
    int g = threadIdx.x;
    if (g >= G) return;
    auto lb = [&](int v) {
        int lo = 0, hi = NN;
        while (lo < hi) { int mid = (lo + hi) >> 1; if (batch[mid] < v) lo = mid + 1; else hi = mid; }
        return lo;
    };
    gcnt[g] = lb(g + 1) - lb(g);
}

// ---------------- W[128][128] fp32 -> Wt[n][k] bf16 (transpose+cast) ---------
__global__ __launch_bounds__(256) void k_wt(const float* __restrict__ W,
                                            ushort* __restrict__ Wt) {
    int t = threadIdx.x;
    for (int i = t; i < FDIM * FDIM; i += 256) {
        int k = i >> 7, n = i & 127;
        Wt[n * FDIM + k] = f2bf(W[i]);
    }
}

// ---------------- bf16 MFMA GEMM: H[N,128] = X[N,128] @ Wt^T -----------------
__global__ __launch_bounds__(256) void k_gemm(const float* __restrict__ X,
                                              const ushort* __restrict__ Wt,
                                              ushort* __restrict__ H, int N) {
    int t = threadIdx.x;
    int wave = t >> 6, l = t & 63;
    int m = l & 15, kg = (l >> 4) * 8;
    int r0 = blockIdx.x * 64 + wave * 16;
    int row = r0 + m;
    short8v a[4];
    if (row < N) {
#pragma unroll
        for (int ks = 0; ks < 4; ks++) {
            const float* xp = X + (size_t)row * FDIM + ks * 32 + kg;
            float4 f0 = *(const float4*)xp;
            float4 f1 = *(const float4*)(xp + 4);
            short8v av;
            av[0] = (short)f2bf(f0.x); av[1] = (short)f2bf(f0.y);
            av[2] = (short)f2bf(f0.z); av[3] = (short)f2bf(f0.w);
            av[4] = (short)f2bf(f1.x); av[5] = (short)f2bf(f1.y);
            av[6] = (short)f2bf(f1.z); av[7] = (short)f2bf(f1.w);
            a[ks] = av;
        }
    } else {
#pragma unroll
        for (int ks = 0; ks < 4; ks++) a[ks] = (short8v)0;
    }
    int orow = r0 + (l >> 4) * 4;
#pragma unroll
    for (int c = 0; c < 8; c++) {
        f32x4 acc = {0.f, 0.f, 0.f, 0.f};
#pragma unroll
        for (int ks = 0; ks < 4; ks++) {
            short8v b = *(const short8v*)(Wt + (size_t)(c * 16 + m) * FDIM + ks * 32 + kg);
            acc = __builtin_amdgcn_mfma_f32_16x16x32_bf16(a[ks], b, acc, 0, 0, 0);
        }
#pragma unroll
        for (int j = 0; j < 4; j++)
            if (orow + j < N) H[(size_t)(orow + j) * FDIM + c * 16 + m] = f2bf(acc[j]);
    }
}

// ---------------- gather aggregation (bf16 H, uint2 csr) ---------------------
// 1 node per wave-iter; 4 edge-slots (eg = l>>4), 16 lanes x 8 bf16 feats;
// butterfly shfl reduce over edge-slots.
// RELU: bias+relu, store Z.  POOL: no bias, pool rows into psum[batch[n]]
// via per-block LDS accumulator (batch sorted -> 1 graph per block typical).
template <int RELU, int POOL>
__global__ __launch_bounds__(256) void k_agg(const ushort* __restrict__ H,
                                             const int* __restrict__ rowptr,
                                             const uint2* __restrict__ csr,
                                             const float* __restrict__ dinv,
                                             const float* __restrict__ bias,
                                             ushort* __restrict__ Z,
                                             const int* __restrict__ batch,
                                             float* __restrict__ psum, int NN) {
    __shared__ float pool[FDIM];
    int t = threadIdx.x;
    int wave = t >> 6, l = t & 63;
    int eg = l >> 4, li = l & 15;
    int f0 = li * 8;
    int gmin = 0;
    if (POOL) {
        if (t < FDIM) pool[t] = 0.0f;
        gmin = batch[blockIdx.x * 16];
        __syncthreads();
    }

    for (int it = 0; it < 4; ++it) {
        int n = blockIdx.x * 16 + wave * 4 + it;
        if (n >= NN) continue;
        float acc[8];
        if (eg == 0) {
            float di = dinv[n];
            float sw = di * di;
            uint4 hv = *(const uint4*)(H + (size_t)n * FDIM + f0);
            acc[0] = sw * bf2f_lo(hv.x); acc[1] = sw * bf2f_hi(hv.x);
            acc[2] = sw * bf2f_lo(hv.y); acc[3] = sw * bf2f_hi(hv.y);
            acc[4] = sw * bf2f_lo(hv.z); acc[5] = sw * bf2f_hi(hv.z);
            acc[6] = sw * bf2f_lo(hv.w); acc[7] = sw * bf2f_hi(hv.w);
        } else {
#pragma unroll
            for (int j = 0; j < 8; j++) acc[j] = 0.0f;
        }
        int rs = rowptr[n], re = rowptr[n + 1];
#pragma unroll 2
        for (int e = rs; e < re; e += 8) {
            int i0 = e + eg, i1 = e + 4 + eg;
            int c0 = min(i0, re - 1), c1 = min(i1, re - 1);
            uint2 p0 = csr[c0], p1 = csr[c1];
            int s0 = (int)p0.x, s1 = (int)p1.x;
            float w0 = (i0 < re) ? __uint_as_float(p0.y) : 0.0f;
            float w1 = (i1 < re) ? __uint_as_float(p1.y) : 0.0f;
            uint4 v0 = *(const uint4*)(H + (size_t)s0 * FDIM + f0);
            uint4 v1 = *(const uint4*)(H + (size_t)s1 * FDIM + f0);
            acc[0] = fmaf(w0, bf2f_lo(v0.x), acc[0]);
            acc[1] = fmaf(w0, bf2f_hi(v0.x), acc[1]);
            acc[2] = fmaf(w0, bf2f_lo(v0.y), acc[2]);
            acc[3] = fmaf(w0, bf2f_hi(v0.y), acc[3]);
            acc[4] = fmaf(w0, bf2f_lo(v0.z), acc[4]);
            acc[5] = fmaf(w0, bf2f_hi(v0.z), acc[5]);
            acc[6] = fmaf(w0, bf2f_lo(v0.w), acc[6]);
            acc[7] = fmaf(w0, bf2f_hi(v0.w), acc[7]);
            acc[0] = fmaf(w1, bf2f_lo(v1.x), acc[0]);
            acc[1] = fmaf(w1, bf2f_hi(v1.x), acc[1]);
            acc[2] = fmaf(w1, bf2f_lo(v1.y), acc[2]);
            acc[3] = fmaf(w1, bf2f_hi(v1.y), acc[3]);
            acc[4] = fmaf(w1, bf2f_lo(v1.z), acc[4]);
            acc[5] = fmaf(w1, bf2f_hi(v1.z), acc[5]);
            acc[6] = fmaf(w1, bf2f_lo(v1.w), acc[6]);
            acc[7] = fmaf(w1, bf2f_hi(v1.w), acc[7]);
        }
#pragma unroll
        for (int j = 0; j < 8; j++) {
            acc[j] += __shfl_xor(acc[j], 16);
            acc[j] += __shfl_xor(acc[j], 32);
        }
        if (eg == 0) {
            if (POOL) {
                int g = batch[n];
                if (g == gmin) {
#pragma unroll
                    for (int j = 0; j < 8; j++) atomicAdd(&pool[f0 + j], acc[j]);
                } else {
#pragma unroll
                    for (int j = 0; j < 8; j++) atomicAdd(&psum[g * FDIM + f0 + j], acc[j]);
                }
            } else {
#pragma unroll
                for (int j = 0; j < 8; j++) acc[j] = acc[j] + bias[f0 + j];
                if (RELU) {
#pragma unroll
                    for (int j = 0; j < 8; j++) acc[j] = fmaxf(acc[j], 0.0f);
                }
                uint4 o;
                o.x = (uint)f2bf(acc[0]) | ((uint)f2bf(acc[1]) << 16);
                o.y = (uint)f2bf(acc[2]) | ((uint)f2bf(acc[3]) << 16);
                o.z = (uint)f2bf(acc[4]) | ((uint)f2bf(acc[5]) << 16);
                o.w = (uint)f2bf(acc[6]) | ((uint)f2bf(acc[7]) << 16);
                *(uint4*)(Z + (size_t)n * FDIM + f0) = o;
            }
        }
    }
    if (POOL) {
        __syncthreads();
        if (t < FDIM) atomicAdd(&psum[gmin * FDIM + t], pool[t]);
    }
}

// ---------------- mean + W2 + b2 + Wfc + bfc (two tiny GEMMs fused) ----------
__global__ __launch_bounds__(128) void k_fc2(const float* __restrict__ psum,
                                             const int* __restrict__ gcnt,
                                             const float* __restrict__ W2,
                                             const float* __restrict__ b2,
                                             const float* __restrict__ Wfc,
                                             const float* __restrict__ bfc,
                                             float* __restrict__ out) {
    __shared__ float p[FDIM], t1[FDIM];
    int g = blockIdx.x, f = threadIdx.x;
    float c = (float)max(gcnt[g], 1);
    p[f] = psum[g * FDIM + f] / c;
    __syncthreads();
    float acc = b2[f];
#pragma unroll 8
    for (int k = 0; k < FDIM; k++) acc = fmaf(p[k], W2[k * FDIM + f], acc);
    t1[f] = acc;
    __syncthreads();
    float acc2 = bfc[f];
#pragma unroll 8
    for (int k = 0; k < FDIM; k++) acc2 = fmaf(t1[k], Wfc[k * FDIM + f], acc2);
    out[g * FDIM + f] = acc2;
}

extern "C" void kernel_launch(void* const* d_in, const int* in_sizes, int n_in,
                              void* d_out, int out_size, void* d_ws, size_t ws_size,
                              hipStream_t stream) {
    const float* x    = (const float*)d_in[0];
    const int*   ei   = (const int*)d_in[1];
    const float* ew   = (const float*)d_in[2];
    const int*   batch= (const int*)d_in[3];
    const float* W1   = (const float*)d_in[4];
    const float* b1   = (const float*)d_in[5];
    const float* W2   = (const float*)d_in[6];
    const float* b2   = (const float*)d_in[7];
    const float* Wfc  = (const float*)d_in[8];
    const float* bfc  = (const float*)d_in[9];
    float* out = (float*)d_out;

    int E  = in_sizes[2];       // 1,600,000
    int NN = in_sizes[3];       // 100,000
    int G  = out_size / FDIM;   // 64

    const int* src = ei;
    const int* dst = ei + E;

    char* ws = (char*)d_ws;
    size_t off = 0;
    auto alloc = [&](size_t bytes) -> void* {
        void* p = ws + off;
        off = (off + bytes + 255) & ~(size_t)255;
        return p;
    };
    unsigned long long* packed = (unsigned long long*)alloc((size_t)NN * 8);
    ushort* aux    = (ushort*)alloc((size_t)E * 2);
    int*   cnt     = (int*)alloc((size_t)NN * 4);
    float* dinv    = (float*)alloc((size_t)NN * 4);
    int*   rowptr  = (int*)alloc((size_t)(NN + 1) * 4);
    int*   bsumA   = (int*)alloc(256 * 4);
    int*   boffA   = (int*)alloc(256 * 4);
    uint2* csr     = (uint2*)alloc((size_t)E * 8);
    float* psum    = (float*)alloc((size_t)G * FDIM * 4);
    int*   gcnt    = (int*)alloc((size_t)G * 4);
    ushort* Bh     = (ushort*)alloc((size_t)NN * FDIM * 2);
    ushort* Bz     = (ushort*)alloc((size_t)NN * FDIM * 2);
    ushort* Wt1    = (ushort*)alloc((size_t)FDIM * FDIM * 2);
    (void)ws_size; (void)n_in;

    int nbN = (NN + 255) / 256;
    int nbE = (E + 255) / 256;
    int NB  = (NN + 1023) / 1024;   // 98

    k_init<<<nbN, 256, 0, stream>>>(packed, psum, NN, G * FDIM);
    k_hist<<<nbE, 256, 0, stream>>>(dst, ew, packed, aux, E);
    k_merge<<<nbN, 256, 0, stream>>>(packed, cnt, dinv, NN);
    k_bsum<<<NB, 256, 0, stream>>>(cnt, bsumA, NN);
    k_btops<<<1, 256, 0, stream>>>(bsumA, boffA, rowptr, NB, NN);
    k_scan<<<NB, 256, 0, stream>>>(cnt, boffA, rowptr, NN);
    k_fill<<<nbE, 256, 0, stream>>>(src, dst, ew, aux, dinv, rowptr, csr, E);
    k_gcnt<<<1, 64, 0, stream>>>(batch, gcnt, NN, G);
    k_wt<<<1, 256, 0, stream>>>(W1, Wt1);

    int nbG = (NN + 63) / 64;
    int nbA = (NN + 15) / 16;
    // layer 1: h1 = x@W1 ; z1 = relu(Agg(h1)+b1)
    k_gemm<<<nbG, 256, 0, stream>>>(x, Wt1, Bh, NN);
    k_agg<1, 0><<<nbA, 256, 0, stream>>>(Bh, rowptr, csr, dinv, b1, Bz,
                                         batch, psum, NN);
    // layer 2 pooled: psum[g] = sum_{d in g} (A_hat z1)[d]  (same CSR)
    k_agg<0, 1><<<nbA, 256, 0, stream>>>(Bz, rowptr, csr, dinv, nullptr, nullptr,
                                         batch, psum, NN);
    // out = ((psum/cnt)@W2 + b2)@Wfc + bfc
    k_fc2<<<G, 128, 0, stream>>>(psum, gcnt, W2, b2, Wfc, bfc, out);
}